// Round 2
// baseline (703.153 us; speedup 1.0000x reference)
//
#include <hip/hip_runtime.h>
#include <stdint.h>

#define Nn 8192
#define Dd 1024
#define Cc_ 1000
#define KCHUNK 2048   // keys per attention chunk (4 chunks)

typedef __bf16 bf16x8 __attribute__((ext_vector_type(8)));
typedef float f32x4 __attribute__((ext_vector_type(4)));
typedef const __attribute__((address_space(1))) void* gas1_t;
typedef __attribute__((address_space(3))) void* las3_t;

__device__ __forceinline__ unsigned short f2bf(float f) {
  unsigned u = __float_as_uint(f);
  u = (u + 0x7fffu + ((u >> 16) & 1u)) >> 16;  // RNE
  return (unsigned short)u;
}
__device__ __forceinline__ float bf2f(unsigned short h) {
  return __uint_as_float(((unsigned)h) << 16);
}
__device__ __forceinline__ void cp16(const void* g, void* l) {
  __builtin_amdgcn_global_load_lds((gas1_t)g, (las3_t)l, 16, 0, 0);
}
__device__ __forceinline__ float wred_sum(float v) {
#pragma unroll
  for (int m = 32; m; m >>= 1) v += __shfl_xor(v, m, 64);
  return v;
}

// ---------------------------------------------------------------------------
// C[r][c] = alpha*(A[M][K] @ Bt[*][K]^T)[r][c] (+bias) (exp) (+=Cold)
// A row stride lda, Bt row stride ldb, C row stride Nout.
// 128x128 tile, 4 waves (2x2 of 64x64), 16x16x32 bf16 MFMA, BK=32.
// LDS [128 rows][4 k-blocks of 8 bf16] with XOR swizzle phys_q = q ^ ((r>>1)&3)
// -> conflict-free ds_read_b128 frags AND contiguous lane*16 staging.
// Grid (M/128, ceil(Nout/128)); Bt must have ceil128(Nout) valid rows;
// stores guarded by col < Nout.
// ---------------------------------------------------------------------------
template <int OBF16, int EXPO, int ACCUM, int BROW>
__global__ __launch_bounds__(256, 2) void gemm_bt(
    const unsigned short* __restrict__ A,
    const unsigned short* __restrict__ Bt,
    const float* __restrict__ bias,
    void* __restrict__ Cout,
    int K, int Nout, int lda, int ldb, float alpha) {
  __shared__ __attribute__((aligned(16))) unsigned short sA[4096];
  __shared__ __attribute__((aligned(16))) unsigned short sB[4096];

  const int tid = threadIdx.x;
  const int lane = tid & 63;
  const int wave = tid >> 6;
  const int wr = (wave >> 1) << 6;
  const int wc = (wave & 1) << 6;
  const long row0 = (long)blockIdx.x << 7;
  const long col0 = (long)blockIdx.y << 7;

  const int srow = (wave << 4) + (lane >> 2);            // rows 0..63 of tile
  const int sq = (lane & 3) ^ ((lane >> 3) & 3);         // logical k-block
  const unsigned short* ga1 = A + (row0 + srow) * lda + sq * 8;
  const unsigned short* ga2 = ga1 + (long)64 * lda;
  const unsigned short* gb1 = Bt + (col0 + srow) * ldb + sq * 8;
  const unsigned short* gb2 = gb1 + (long)64 * ldb;
  unsigned short* la1 = &sA[wave * 512];
  unsigned short* la2 = &sA[2048 + wave * 512];
  unsigned short* lb1 = &sB[wave * 512];
  unsigned short* lb2 = &sB[2048 + wave * 512];

  f32x4 acc[4][4] = {};

  const int fq = ((lane >> 4) ^ ((lane >> 1) & 3)) << 3;  // phys block * 8
  const int am = wr + (lane & 15);
  const int bn = wc + (lane & 15);

  for (int k0 = 0; k0 < K; k0 += 32) {
    __syncthreads();  // prior iter's LDS reads done
    cp16(ga1, la1);
    cp16(ga2, la2);
    cp16(gb1, lb1);
    cp16(gb2, lb2);
    ga1 += 32; ga2 += 32; gb1 += 32; gb2 += 32;
    __syncthreads();  // vmcnt drained before barrier -> staging visible

    bf16x8 af[4], bfr[4];
#pragma unroll
    for (int i = 0; i < 4; ++i)
      af[i] = *(const bf16x8*)&sA[((am + (i << 4)) << 5) + fq];
#pragma unroll
    for (int j = 0; j < 4; ++j)
      bfr[j] = *(const bf16x8*)&sB[((bn + (j << 4)) << 5) + fq];
#pragma unroll
    for (int i = 0; i < 4; ++i)
#pragma unroll
      for (int j = 0; j < 4; ++j)
        acc[i][j] = __builtin_amdgcn_mfma_f32_16x16x32_bf16(af[i], bfr[j], acc[i][j], 0, 0, 0);
  }

  // C/D layout: col = lane&15, row = (lane>>4)*4 + reg   [m89-verified]
  const int cr = (lane >> 4) << 2;
  const int ccol = lane & 15;
#pragma unroll
  for (int j = 0; j < 4; ++j) {
    const long col = col0 + wc + (j << 4) + ccol;
    if (col < Nout) {
      float bvc = 0.f;
      if (!BROW && bias) bvc = bias[col];
#pragma unroll
      for (int i = 0; i < 4; ++i) {
        const long rowb = row0 + wr + (i << 4) + cr;
#pragma unroll
        for (int r = 0; r < 4; ++r) {
          float v = acc[i][j][r] * alpha + bvc;
          if (BROW) v += bias[rowb + r];
          if (EXPO) v = __expf(v);
          const long idx = (rowb + r) * Nout + col;
          if (OBF16) {
            ((unsigned short*)Cout)[idx] = f2bf(v);
          } else {
            if (ACCUM) v += ((float*)Cout)[idx];
            ((float*)Cout)[idx] = v;
          }
        }
      }
    }
  }
}

// ---------------------------------------------------------------------------
__global__ __launch_bounds__(256) void cast_f32_to_bf16(
    const float* __restrict__ in, unsigned short* __restrict__ out, int n) {
  int i = (blockIdx.x * 256 + threadIdx.x) * 4;
  if (i + 3 < n) {
    float4 v = *(const float4*)(in + i);
    ushort4 o;
    o.x = f2bf(v.x); o.y = f2bf(v.y); o.z = f2bf(v.z); o.w = f2bf(v.w);
    *(ushort4*)(out + i) = o;
  }
}

__global__ __launch_bounds__(256) void zero_f32(float* __restrict__ p, int n) {
  int i = blockIdx.x * 256 + threadIdx.x;
  if (i < n) p[i] = 0.f;
}

__global__ __launch_bounds__(1) void sentinel_kernel(float* __restrict__ out) {
  out[0] = -12345.0f;
}

// in[R][C] fp32 -> out[Cpad][R] bf16, rows C..Cpad-1 zeroed. block (32,8)
__global__ void transpose_f32_to_bf16(const float* __restrict__ in,
                                      unsigned short* __restrict__ out,
                                      int R, int C, int Cpad) {
  __shared__ float tile[32][33];
  int c0 = blockIdx.x * 32, r0 = blockIdx.y * 32;
  int tx = threadIdx.x, ty = threadIdx.y;
  for (int i = ty; i < 32; i += 8) {
    int r = r0 + i, c = c0 + tx;
    tile[i][tx] = (r < R && c < C) ? in[(size_t)r * C + c] : 0.f;
  }
  __syncthreads();
  for (int i = ty; i < 32; i += 8) {
    int oc = c0 + i, orr = r0 + tx;
    if (oc < Cpad && orr < R) out[(size_t)oc * R + orr] = f2bf(tile[tx][i]);
  }
}

// l[row] += sum_j S[row][j], S bf16 [8192][ncols], one block per row
__global__ __launch_bounds__(256) void rowsum_acc(
    const unsigned short* __restrict__ S, float* __restrict__ l, int ncols) {
  const int tid = threadIdx.x;
  const unsigned short* p = S + (size_t)blockIdx.x * ncols;
  __shared__ float red[4];
  float s = 0.f;
  for (int j = tid * 4; j < ncols; j += 1024) {
    ushort4 v = *(const ushort4*)(p + j);
    s += (bf2f(v.x) + bf2f(v.y)) + (bf2f(v.z) + bf2f(v.w));
  }
  s = wred_sum(s);
  if ((tid & 63) == 0) red[tid >> 6] = s;
  __syncthreads();
  if (tid == 0) l[blockIdx.x] += (red[0] + red[1]) + (red[2] + red[3]);
}

// beta = sigmoid(inv_l*sum(av*(Wb0+Wb2)) + sum(xr*(Wb1-Wb2)) + bb)
// u = beta*xr + (1-beta)*av*inv_l   (bf16 out)
__global__ __launch_bounds__(256) void beta_combine(
    const unsigned short* __restrict__ xr, const float* __restrict__ av,
    const float* __restrict__ l, const float* __restrict__ Wb,
    const float* __restrict__ bb, unsigned short* __restrict__ u) {
  const int row = blockIdx.x;
  const int tid = threadIdx.x;
  const unsigned short* xp = xr + (size_t)row * Dd;
  const float* ap = av + (size_t)row * Dd;
  const float invl = 1.f / l[row];
  __shared__ float red[8];
  float sa = 0.f, sx = 0.f;
  for (int j = tid; j < Dd; j += 256) {
    float w2 = Wb[2 * Dd + j];
    sa += ap[j] * (Wb[j] + w2);
    sx += bf2f(xp[j]) * (Wb[Dd + j] - w2);
  }
  sa = wred_sum(sa);
  sx = wred_sum(sx);
  if ((tid & 63) == 0) {
    red[tid >> 6] = sa;
    red[4 + (tid >> 6)] = sx;
  }
  __syncthreads();
  const float s = (red[0] + red[1] + red[2] + red[3]) * invl +
                  (red[4] + red[5] + red[6] + red[7]) + bb[0];
  const float beta = 1.f / (1.f + __expf(-s));
  unsigned short* up = u + (size_t)row * Dd;
  for (int j = tid; j < Dd; j += 256)
    up[j] = f2bf(beta * bf2f(xp[j]) + (1.f - beta) * ap[j] * invl);
}

// ---------------------------------------------------------------------------
extern "C" void kernel_launch(void* const* d_in, const int* in_sizes, int n_in,
                              void* d_out, int out_size, void* d_ws, size_t ws_size,
                              hipStream_t stream) {
  (void)in_sizes; (void)n_in; (void)out_size;
  const float* x      = (const float*)d_in[0];
  const float* W_skip = (const float*)d_in[1];
  const float* b_skip = (const float*)d_in[2];
  const float* W_q    = (const float*)d_in[3];
  const float* b_q    = (const float*)d_in[4];
  const float* W_k    = (const float*)d_in[5];
  const float* b_k    = (const float*)d_in[6];
  const float* W_v    = (const float*)d_in[7];
  const float* b_v    = (const float*)d_in[8];
  const float* W_beta = (const float*)d_in[9];
  const float* b_beta = (const float*)d_in[10];
  const float* W_fc   = (const float*)d_in[11];
  const float* b_fc   = (const float*)d_in[12];
  float* out = (float*)d_out;

  char* w = (char*)d_ws;
  size_t off = 0;
  auto take = [&](size_t b) -> void* {
    void* p = w + off;
    off += (b + 255) & ~(size_t)255;
    return p;
  };
  const size_t szND2 = (size_t)Nn * Dd * 2;
  const size_t szDD2 = (size_t)Dd * Dd * 2;
  unsigned short* xb  = (unsigned short*)take(szND2);   // x bf16; reused as ub
  unsigned short* qb  = (unsigned short*)take(szND2);
  unsigned short* kb  = (unsigned short*)take(szND2);
  unsigned short* vtb = (unsigned short*)take(szND2);   // v^T [D][N]
  unsigned short* xrb = (unsigned short*)take(szND2);   // x_r bf16
  float* avf          = (float*)take((size_t)Nn * Dd * 4);  // unnormalized P@V
  unsigned short* wst = (unsigned short*)take(szDD2);   // W^T [out][in]
  unsigned short* wqt = (unsigned short*)take(szDD2);
  unsigned short* wkt = (unsigned short*)take(szDD2);
  unsigned short* wvt = (unsigned short*)take(szDD2);
  unsigned short* wft = (unsigned short*)take(szDD2);   // padded 1000->1024 cols
  unsigned short* Sc  = (unsigned short*)take((size_t)Nn * KCHUNK * 2);
  float* lsum         = (float*)take((size_t)Nn * 4);
  unsigned short* ub  = xb;                             // overlay (xb dead)

  if (off > ws_size) {  // workspace too small -> unmistakable sentinel
    sentinel_kernel<<<1, 1, 0, stream>>>(out);
    return;
  }

  dim3 tb(32, 8);
  cast_f32_to_bf16<<<Nn * Dd / 1024, 256, 0, stream>>>(x, xb, Nn * Dd);
  transpose_f32_to_bf16<<<dim3(32, 32), tb, 0, stream>>>(W_skip, wst, Dd, Dd, Dd);
  transpose_f32_to_bf16<<<dim3(32, 32), tb, 0, stream>>>(W_q, wqt, Dd, Dd, Dd);
  transpose_f32_to_bf16<<<dim3(32, 32), tb, 0, stream>>>(W_k, wkt, Dd, Dd, Dd);
  transpose_f32_to_bf16<<<dim3(32, 32), tb, 0, stream>>>(W_v, wvt, Dd, Dd, Dd);
  transpose_f32_to_bf16<<<dim3(32, 32), tb, 0, stream>>>(W_fc, wft, Dd, Cc_, 1024);

  // projections: q, k, x_r (bias per col); v^T = W_v^T @ x^T (bias per row)
  gemm_bt<1,0,0,0><<<dim3(64, 8), 256, 0, stream>>>(xb, wqt, b_q, qb, Dd, Dd, Dd, Dd, 1.f);
  gemm_bt<1,0,0,0><<<dim3(64, 8), 256, 0, stream>>>(xb, wkt, b_k, kb, Dd, Dd, Dd, Dd, 1.f);
  gemm_bt<1,0,0,0><<<dim3(64, 8), 256, 0, stream>>>(xb, wst, b_skip, xrb, Dd, Dd, Dd, Dd, 1.f);
  gemm_bt<1,0,0,1><<<dim3(8, 64), 256, 0, stream>>>(wvt, xb, b_v, vtb, Dd, Nn, Dd, Dd, 1.f);

  zero_f32<<<Nn / 256, 256, 0, stream>>>(lsum, Nn);

  // chunked attention over keys; no-max softmax (|scores/32| <~ 3, fp32-safe)
  for (int c = 0; c < Nn / KCHUNK; ++c) {
    const unsigned short* kc = kb + (size_t)c * KCHUNK * Dd;
    const unsigned short* vc = vtb + (size_t)c * KCHUNK;
    // P_c = exp(q @ k_c^T / 32), bf16 [8192][KCHUNK]
    gemm_bt<1,1,0,0><<<dim3(64, KCHUNK / 128), 256, 0, stream>>>(
        qb, kc, nullptr, Sc, Dd, KCHUNK, Dd, Dd, 0.03125f);
    rowsum_acc<<<Nn, 256, 0, stream>>>(Sc, lsum, KCHUNK);
    // avf (+)= P_c @ v_c
    if (c == 0)
      gemm_bt<0,0,0,0><<<dim3(64, 8), 256, 0, stream>>>(
          Sc, vc, nullptr, avf, KCHUNK, Dd, KCHUNK, Nn, 1.f);
    else
      gemm_bt<0,0,1,0><<<dim3(64, 8), 256, 0, stream>>>(
          Sc, vc, nullptr, avf, KCHUNK, Dd, KCHUNK, Nn, 1.f);
  }

  beta_combine<<<Nn, 256, 0, stream>>>(xrb, avf, lsum, W_beta, b_beta, ub);

  gemm_bt<0,0,0,0><<<dim3(64, 8), 256, 0, stream>>>(ub, wft, b_fc, out, Dd, Cc_, Dd, Dd, 1.f);
}

// Round 3
// 606.166 us; speedup vs baseline: 1.1600x; 1.1600x over previous
//
#include <hip/hip_runtime.h>
#include <stdint.h>

#define Nn 8192
#define Dd 1024
#define Cc_ 1000
#define KCHUNK 2048   // keys per attention chunk (4 chunks)

typedef __bf16 bf16x8 __attribute__((ext_vector_type(8)));
typedef float f32x4 __attribute__((ext_vector_type(4)));
typedef const __attribute__((address_space(1))) void* gas1_t;
typedef __attribute__((address_space(3))) void* las3_t;

__device__ __forceinline__ unsigned short f2bf(float f) {
  unsigned u = __float_as_uint(f);
  u = (u + 0x7fffu + ((u >> 16) & 1u)) >> 16;  // RNE
  return (unsigned short)u;
}
__device__ __forceinline__ float bf2f(unsigned short h) {
  return __uint_as_float(((unsigned)h) << 16);
}
__device__ __forceinline__ void cp16(const void* g, void* l) {
  __builtin_amdgcn_global_load_lds((gas1_t)g, (las3_t)l, 16, 0, 0);
}
__device__ __forceinline__ float wred_sum(float v) {
#pragma unroll
  for (int m = 32; m; m >>= 1) v += __shfl_xor(v, m, 64);
  return v;
}

// ---------------------------------------------------------------------------
// C[r][c] = alpha*(A[M][K] @ Bt[*][K]^T)[r][c] (+bias) (exp+rowsum) (+=Cold)
// BK=64: two 32-wide sub-tiles per barrier pair (halves drain events).
// Each 4096-short sub-tile keeps round-1's verified layout: [128 rows][4
// k-blocks of 8 bf16], XOR swizzle phys_q = q ^ swz(row) -> conflict-free
// ds_read_b128 AND wave-contiguous lane*16 global_load_lds staging.
// Grid (M/128, ceil(Nout/128)); Bt needs ceil128(Nout) valid rows; K%64==0.
// ER: epilogue v=exp(alpha*acc), bf16 store, per-row sums atomicAdd -> lsum.
// ---------------------------------------------------------------------------
template <int OBF16, int ER, int ACCUM, int BROW>
__global__ __launch_bounds__(256, 2) void gemm_bt(
    const unsigned short* __restrict__ A,
    const unsigned short* __restrict__ Bt,
    const float* __restrict__ bias,
    void* __restrict__ Cout,
    int K, int Nout, int lda, int ldb, float alpha,
    float* __restrict__ lsum) {
  __shared__ __attribute__((aligned(16))) unsigned short sA[8192];
  __shared__ __attribute__((aligned(16))) unsigned short sB[8192];

  const int tid = threadIdx.x;
  const int lane = tid & 63;
  const int wave = tid >> 6;
  const int wr = (wave >> 1) << 6;
  const int wc = (wave & 1) << 6;
  const long row0 = (long)blockIdx.x << 7;
  const long col0 = (long)blockIdx.y << 7;

  const int srow = (wave << 4) + (lane >> 2);            // rows 0..63 of tile
  const int sq = (lane & 3) ^ ((lane >> 3) & 3);         // logical k-block
  const unsigned short* ga1 = A + (row0 + srow) * lda + sq * 8;
  const unsigned short* ga2 = ga1 + (long)64 * lda;
  const unsigned short* gb1 = Bt + (col0 + srow) * ldb + sq * 8;
  const unsigned short* gb2 = gb1 + (long)64 * ldb;
  unsigned short* la1 = &sA[wave * 512];
  unsigned short* la2 = &sA[2048 + wave * 512];
  unsigned short* lb1 = &sB[wave * 512];
  unsigned short* lb2 = &sB[2048 + wave * 512];

  f32x4 acc[4][4] = {};

  const int fq = ((lane >> 4) ^ ((lane >> 1) & 3)) << 3;  // phys block * 8
  const int am = wr + (lane & 15);
  const int bn = wc + (lane & 15);

  for (int k0 = 0; k0 < K; k0 += 64) {
    __syncthreads();  // prior iter's LDS reads done
    cp16(ga1, la1);          cp16(ga2, la2);           // A half0 (k 0-31)
    cp16(ga1 + 32, la1 + 4096); cp16(ga2 + 32, la2 + 4096);  // A half1
    cp16(gb1, lb1);          cp16(gb2, lb2);           // B half0
    cp16(gb1 + 32, lb1 + 4096); cp16(gb2 + 32, lb2 + 4096);  // B half1
    ga1 += 64; ga2 += 64; gb1 += 64; gb2 += 64;
    __syncthreads();  // vmcnt drained before barrier -> staging visible

#pragma unroll
    for (int h = 0; h < 2; ++h) {
      const unsigned short* bA = &sA[h << 12];
      const unsigned short* bB = &sB[h << 12];
      bf16x8 af[4], bfr[4];
#pragma unroll
      for (int i = 0; i < 4; ++i)
        af[i] = *(const bf16x8*)&bA[((am + (i << 4)) << 5) + fq];
#pragma unroll
      for (int j = 0; j < 4; ++j)
        bfr[j] = *(const bf16x8*)&bB[((bn + (j << 4)) << 5) + fq];
#pragma unroll
      for (int i = 0; i < 4; ++i)
#pragma unroll
        for (int j = 0; j < 4; ++j)
          acc[i][j] = __builtin_amdgcn_mfma_f32_16x16x32_bf16(af[i], bfr[j], acc[i][j], 0, 0, 0);
    }
  }

  // C/D layout: col = lane&15, row = (lane>>4)*4 + reg   [m89-verified]
  const int cr = (lane >> 4) << 2;
  const int ccol = lane & 15;
  if (ER) {
    // exp + bf16 store + fused row-sum (full tiles only; no col guard)
    float rs[4][4];
#pragma unroll
    for (int i = 0; i < 4; ++i)
#pragma unroll
      for (int r = 0; r < 4; ++r) rs[i][r] = 0.f;
#pragma unroll
    for (int j = 0; j < 4; ++j) {
      const long col = col0 + wc + (j << 4) + ccol;
#pragma unroll
      for (int i = 0; i < 4; ++i) {
        const long rowb = row0 + wr + (i << 4) + cr;
#pragma unroll
        for (int r = 0; r < 4; ++r) {
          float v = __expf(acc[i][j][r] * alpha);
          rs[i][r] += v;
          ((unsigned short*)Cout)[(rowb + r) * (long)Nout + col] = f2bf(v);
        }
      }
    }
#pragma unroll
    for (int i = 0; i < 4; ++i)
#pragma unroll
      for (int r = 0; r < 4; ++r) {
        float s = rs[i][r];
#pragma unroll
        for (int m = 1; m < 16; m <<= 1) s += __shfl_xor(s, m, 64);
        if (ccol == 0)
          atomicAdd(&lsum[row0 + wr + (i << 4) + cr + r], s);
      }
  } else {
#pragma unroll
    for (int j = 0; j < 4; ++j) {
      const long col = col0 + wc + (j << 4) + ccol;
      if (col < Nout) {
        float bvc = 0.f;
        if (!BROW && bias) bvc = bias[col];
#pragma unroll
        for (int i = 0; i < 4; ++i) {
          const long rowb = row0 + wr + (i << 4) + cr;
#pragma unroll
          for (int r = 0; r < 4; ++r) {
            float v = acc[i][j][r] * alpha + bvc;
            if (BROW) v += bias[rowb + r];
            const long idx = (rowb + r) * (long)Nout + col;
            if (OBF16) {
              if (ACCUM) v += bf2f(((unsigned short*)Cout)[idx]);
              ((unsigned short*)Cout)[idx] = f2bf(v);
            } else {
              ((float*)Cout)[idx] = v;
            }
          }
        }
      }
    }
  }
}

// ---------------------------------------------------------------------------
__global__ __launch_bounds__(256) void cast_f32_to_bf16(
    const float* __restrict__ in, unsigned short* __restrict__ out, int n) {
  int i = (blockIdx.x * 256 + threadIdx.x) * 4;
  if (i + 3 < n) {
    float4 v = *(const float4*)(in + i);
    ushort4 o;
    o.x = f2bf(v.x); o.y = f2bf(v.y); o.z = f2bf(v.z); o.w = f2bf(v.w);
    *(ushort4*)(out + i) = o;
  }
}

__global__ __launch_bounds__(256) void zero_f32(float* __restrict__ p, int n) {
  int i = blockIdx.x * 256 + threadIdx.x;
  if (i < n) p[i] = 0.f;
}

__global__ __launch_bounds__(256) void cat_bias3(
    const float* __restrict__ a, const float* __restrict__ b,
    const float* __restrict__ c, float* __restrict__ o) {
  int i = blockIdx.x * 256 + threadIdx.x;
  if (i < 1024) o[i] = a[i];
  else if (i < 2048) o[i] = b[i - 1024];
  else if (i < 3072) o[i] = c[i - 2048];
}

__global__ __launch_bounds__(1) void sentinel_kernel(float* __restrict__ out) {
  out[0] = -12345.0f;
}

// in[R][C] fp32 -> out[Cpad][R] bf16, rows C..Cpad-1 zeroed. block (32,8)
__global__ void transpose_f32_to_bf16(const float* __restrict__ in,
                                      unsigned short* __restrict__ out,
                                      int R, int C, int Cpad) {
  __shared__ float tile[32][33];
  int c0 = blockIdx.x * 32, r0 = blockIdx.y * 32;
  int tx = threadIdx.x, ty = threadIdx.y;
  for (int i = ty; i < 32; i += 8) {
    int r = r0 + i, c = c0 + tx;
    tile[i][tx] = (r < R && c < C) ? in[(size_t)r * C + c] : 0.f;
  }
  __syncthreads();
  for (int i = ty; i < 32; i += 8) {
    int oc = c0 + i, orr = r0 + tx;
    if (oc < Cpad && orr < R) out[(size_t)oc * R + orr] = f2bf(tile[tx][i]);
  }
}

// beta = sigmoid(inv_l*sum(av*(Wb0+Wb2)) + sum(xr*(Wb1-Wb2)) + bb)
// u = beta*xr + (1-beta)*av*inv_l   (bf16 out). xr stride 3072, av stride 1024.
__global__ __launch_bounds__(256) void beta_combine(
    const unsigned short* __restrict__ xr, const unsigned short* __restrict__ av,
    const float* __restrict__ l, const float* __restrict__ Wb,
    const float* __restrict__ bb, unsigned short* __restrict__ u) {
  const int row = blockIdx.x;
  const int tid = threadIdx.x;
  const unsigned short* xp = xr + (size_t)row * 3072;
  const unsigned short* ap = av + (size_t)row * Dd;
  const float invl = 1.f / l[row];
  __shared__ float red[8];
  float sa = 0.f, sx = 0.f;
  for (int j = tid; j < Dd; j += 256) {
    float w2 = Wb[2 * Dd + j];
    sa += bf2f(ap[j]) * (Wb[j] + w2);
    sx += bf2f(xp[j]) * (Wb[Dd + j] - w2);
  }
  sa = wred_sum(sa);
  sx = wred_sum(sx);
  if ((tid & 63) == 0) {
    red[tid >> 6] = sa;
    red[4 + (tid >> 6)] = sx;
  }
  __syncthreads();
  const float s = (red[0] + red[1] + red[2] + red[3]) * invl +
                  (red[4] + red[5] + red[6] + red[7]) + bb[0];
  const float beta = 1.f / (1.f + __expf(-s));
  unsigned short* up = u + (size_t)row * Dd;
  for (int j = tid; j < Dd; j += 256)
    up[j] = f2bf(beta * bf2f(xp[j]) + (1.f - beta) * bf2f(ap[j]) * invl);
}

// ---------------------------------------------------------------------------
extern "C" void kernel_launch(void* const* d_in, const int* in_sizes, int n_in,
                              void* d_out, int out_size, void* d_ws, size_t ws_size,
                              hipStream_t stream) {
  (void)in_sizes; (void)n_in; (void)out_size;
  const float* x      = (const float*)d_in[0];
  const float* W_skip = (const float*)d_in[1];
  const float* b_skip = (const float*)d_in[2];
  const float* W_q    = (const float*)d_in[3];
  const float* b_q    = (const float*)d_in[4];
  const float* W_k    = (const float*)d_in[5];
  const float* b_k    = (const float*)d_in[6];
  const float* W_v    = (const float*)d_in[7];
  const float* b_v    = (const float*)d_in[8];
  const float* W_beta = (const float*)d_in[9];
  const float* b_beta = (const float*)d_in[10];
  const float* W_fc   = (const float*)d_in[11];
  const float* b_fc   = (const float*)d_in[12];
  float* out = (float*)d_out;

  char* w = (char*)d_ws;
  size_t off = 0;
  auto take = [&](size_t b) -> void* {
    void* p = w + off;
    off += (b + 255) & ~(size_t)255;
    return p;
  };
  const size_t szND2 = (size_t)Nn * Dd * 2;
  const size_t szDD2 = (size_t)Dd * Dd * 2;
  unsigned short* xb   = (unsigned short*)take(szND2);           // x bf16; reused as ub
  unsigned short* qks  = (unsigned short*)take((size_t)Nn * 3072 * 2);  // [q|k|x_r]
  unsigned short* vtb  = (unsigned short*)take(szND2);           // v^T [D][N]
  unsigned short* avb  = (unsigned short*)take(szND2);           // unnormalized P@V, bf16
  unsigned short* wcat = (unsigned short*)take(3 * szDD2);       // [Wq|Wk|Wskip]^T rows
  unsigned short* wvt  = (unsigned short*)take(szDD2);
  unsigned short* wft  = (unsigned short*)take(szDD2);           // padded 1000->1024
  float* bcat          = (float*)take(3072 * 4);
  unsigned short* Sc   = (unsigned short*)take((size_t)Nn * KCHUNK * 2);
  float* lsum          = (float*)take((size_t)Nn * 4);
  unsigned short* ub   = xb;                                     // overlay (xb dead)

  if (off > ws_size) {  // workspace too small -> unmistakable sentinel
    sentinel_kernel<<<1, 1, 0, stream>>>(out);
    return;
  }

  dim3 tb(32, 8);
  cast_f32_to_bf16<<<Nn * Dd / 1024, 256, 0, stream>>>(x, xb, Nn * Dd);
  transpose_f32_to_bf16<<<dim3(32, 32), tb, 0, stream>>>(W_q, wcat, Dd, Dd, Dd);
  transpose_f32_to_bf16<<<dim3(32, 32), tb, 0, stream>>>(W_k, wcat + (size_t)Dd * Dd, Dd, Dd, Dd);
  transpose_f32_to_bf16<<<dim3(32, 32), tb, 0, stream>>>(W_skip, wcat + (size_t)2 * Dd * Dd, Dd, Dd, Dd);
  transpose_f32_to_bf16<<<dim3(32, 32), tb, 0, stream>>>(W_v, wvt, Dd, Dd, Dd);
  transpose_f32_to_bf16<<<dim3(32, 32), tb, 0, stream>>>(W_fc, wft, Dd, Cc_, 1024);
  cat_bias3<<<12, 256, 0, stream>>>(b_q, b_k, b_skip, bcat);

  // fused q|k|x_r projection: [8192][3072]
  gemm_bt<1,0,0,0><<<dim3(64, 24), 256, 0, stream>>>(
      xb, wcat, bcat, qks, Dd, 3072, Dd, Dd, 1.f, nullptr);
  // v^T = W_v^T @ x^T + b_v (bias per row): [1024][8192]
  gemm_bt<1,0,0,1><<<dim3(8, 64), 256, 0, stream>>>(
      wvt, xb, b_v, vtb, Dd, Nn, Dd, Dd, 1.f, nullptr);

  zero_f32<<<Nn / 256, 256, 0, stream>>>(lsum, Nn);

  // chunked attention over keys; no-max softmax (|scores/32| <~ 3, fp32-safe)
  for (int c = 0; c < Nn / KCHUNK; ++c) {
    const unsigned short* kc = qks + (size_t)c * KCHUNK * 3072 + 1024;
    const unsigned short* vc = vtb + (size_t)c * KCHUNK;
    // P_c = exp(q @ k_c^T / 32) bf16 + fused row-sums into lsum
    gemm_bt<1,1,0,0><<<dim3(64, KCHUNK / 128), 256, 0, stream>>>(
        qks, kc, nullptr, Sc, Dd, KCHUNK, 3072, 3072, 0.03125f, lsum);
    // avb (+)= P_c @ v_c  (bf16 accumulate)
    if (c == 0)
      gemm_bt<1,0,0,0><<<dim3(64, 8), 256, 0, stream>>>(
          Sc, vc, nullptr, avb, KCHUNK, Dd, KCHUNK, Nn, 1.f, nullptr);
    else
      gemm_bt<1,0,1,0><<<dim3(64, 8), 256, 0, stream>>>(
          Sc, vc, nullptr, avb, KCHUNK, Dd, KCHUNK, Nn, 1.f, nullptr);
  }

  beta_combine<<<Nn, 256, 0, stream>>>(qks + 2048, avb, lsum, W_beta, b_beta, ub);

  gemm_bt<0,0,0,0><<<dim3(64, 8), 256, 0, stream>>>(
      ub, wft, b_fc, out, Dd, Cc_, Dd, Dd, 1.f, nullptr);
}

// Round 4
// 563.231 us; speedup vs baseline: 1.2484x; 1.0762x over previous
//
#include <hip/hip_runtime.h>
#include <stdint.h>

#define Nn 8192
#define Dd 1024
#define Cc_ 1000
#define KCHUNK 4096   // keys per attention chunk (2 chunks)

typedef __bf16 bf16x8 __attribute__((ext_vector_type(8)));
typedef float f32x4 __attribute__((ext_vector_type(4)));
typedef const __attribute__((address_space(1))) void* gas1_t;
typedef __attribute__((address_space(3))) void* las3_t;

__device__ __forceinline__ unsigned short f2bf(float f) {
  unsigned u = __float_as_uint(f);
  u = (u + 0x7fffu + ((u >> 16) & 1u)) >> 16;  // RNE
  return (unsigned short)u;
}
__device__ __forceinline__ float bf2f(unsigned short h) {
  return __uint_as_float(((unsigned)h) << 16);
}
__device__ __forceinline__ void cp16(const void* g, void* l) {
  __builtin_amdgcn_global_load_lds((gas1_t)g, (las3_t)l, 16, 0, 0);
}
__device__ __forceinline__ float wred_sum(float v) {
#pragma unroll
  for (int m = 32; m; m >>= 1) v += __shfl_xor(v, m, 64);
  return v;
}

// ---------------------------------------------------------------------------
// C[r][c] = alpha*(A[M][K] @ Bt[*][K]^T)[r][c] (+bias) (exp+rowsum) (+=Cold)
// BK=64: two 32-wide sub-tiles per barrier pair. Each 4096-short sub-tile:
// [128 rows][4 k-blocks of 8 bf16], XOR swizzle phys_q = q ^ swz(row) ->
// conflict-free ds_read_b128 AND wave-contiguous lane*16 global_load_lds.
// launch_bounds(256,4): VGPR 56 + AGPR 64 = 120 <= 128 -> 4 blocks/CU
// (vs round-2's self-inflicted 2) so other blocks' MFMA covers barrier drain.
// Grid (M/128, ceil(Nout/128)); Bt needs ceil128(Nout) valid rows; K%64==0.
// ---------------------------------------------------------------------------
template <int OBF16, int ER, int ACCUM, int BROW>
__global__ __launch_bounds__(256, 4) void gemm_bt(
    const unsigned short* __restrict__ A,
    const unsigned short* __restrict__ Bt,
    const float* __restrict__ bias,
    void* __restrict__ Cout,
    int K, int Nout, int lda, int ldb, float alpha,
    float* __restrict__ lsum) {
  __shared__ __attribute__((aligned(16))) unsigned short sA[8192];
  __shared__ __attribute__((aligned(16))) unsigned short sB[8192];

  const int tid = threadIdx.x;
  const int lane = tid & 63;
  const int wave = tid >> 6;
  const int wr = (wave >> 1) << 6;
  const int wc = (wave & 1) << 6;
  const long row0 = (long)blockIdx.x << 7;
  const long col0 = (long)blockIdx.y << 7;

  const int srow = (wave << 4) + (lane >> 2);            // rows 0..63 of tile
  const int sq = (lane & 3) ^ ((lane >> 3) & 3);         // logical k-block
  const unsigned short* ga1 = A + (row0 + srow) * lda + sq * 8;
  const unsigned short* ga2 = ga1 + (long)64 * lda;
  const unsigned short* gb1 = Bt + (col0 + srow) * ldb + sq * 8;
  const unsigned short* gb2 = gb1 + (long)64 * ldb;
  unsigned short* la1 = &sA[wave * 512];
  unsigned short* la2 = &sA[2048 + wave * 512];
  unsigned short* lb1 = &sB[wave * 512];
  unsigned short* lb2 = &sB[2048 + wave * 512];

  f32x4 acc[4][4] = {};

  const int fq = ((lane >> 4) ^ ((lane >> 1) & 3)) << 3;  // phys block * 8
  const int am = wr + (lane & 15);
  const int bn = wc + (lane & 15);

  for (int k0 = 0; k0 < K; k0 += 64) {
    __syncthreads();  // prior iter's LDS reads done
    cp16(ga1, la1);          cp16(ga2, la2);           // A half0 (k 0-31)
    cp16(ga1 + 32, la1 + 4096); cp16(ga2 + 32, la2 + 4096);  // A half1
    cp16(gb1, lb1);          cp16(gb2, lb2);           // B half0
    cp16(gb1 + 32, lb1 + 4096); cp16(gb2 + 32, lb2 + 4096);  // B half1
    ga1 += 64; ga2 += 64; gb1 += 64; gb2 += 64;
    __syncthreads();  // vmcnt drained before barrier -> staging visible

#pragma unroll
    for (int h = 0; h < 2; ++h) {
      const unsigned short* bA = &sA[h << 12];
      const unsigned short* bB = &sB[h << 12];
      bf16x8 af[4], bfr[4];
#pragma unroll
      for (int i = 0; i < 4; ++i)
        af[i] = *(const bf16x8*)&bA[((am + (i << 4)) << 5) + fq];
#pragma unroll
      for (int j = 0; j < 4; ++j)
        bfr[j] = *(const bf16x8*)&bB[((bn + (j << 4)) << 5) + fq];
#pragma unroll
      for (int i = 0; i < 4; ++i)
#pragma unroll
        for (int j = 0; j < 4; ++j)
          acc[i][j] = __builtin_amdgcn_mfma_f32_16x16x32_bf16(af[i], bfr[j], acc[i][j], 0, 0, 0);
    }
  }

  // C/D layout: col = lane&15, row = (lane>>4)*4 + reg   [m89-verified]
  const int cr = (lane >> 4) << 2;
  const int ccol = lane & 15;
  if (ER) {
    // exp + bf16 store + fused row-sum (full tiles only; no col guard)
    float rs[4][4];
#pragma unroll
    for (int i = 0; i < 4; ++i)
#pragma unroll
      for (int r = 0; r < 4; ++r) rs[i][r] = 0.f;
#pragma unroll
    for (int j = 0; j < 4; ++j) {
      const long col = col0 + wc + (j << 4) + ccol;
#pragma unroll
      for (int i = 0; i < 4; ++i) {
        const long rowb = row0 + wr + (i << 4) + cr;
#pragma unroll
        for (int r = 0; r < 4; ++r) {
          float v = __expf(acc[i][j][r] * alpha);
          rs[i][r] += v;
          ((unsigned short*)Cout)[(rowb + r) * (long)Nout + col] = f2bf(v);
        }
      }
    }
#pragma unroll
    for (int i = 0; i < 4; ++i)
#pragma unroll
      for (int r = 0; r < 4; ++r) {
        float s = rs[i][r];
#pragma unroll
        for (int m = 1; m < 16; m <<= 1) s += __shfl_xor(s, m, 64);
        if (ccol == 0)
          atomicAdd(&lsum[row0 + wr + (i << 4) + cr + r], s);
      }
  } else {
#pragma unroll
    for (int j = 0; j < 4; ++j) {
      const long col = col0 + wc + (j << 4) + ccol;
      if (col < Nout) {
        float bvc = 0.f;
        if (!BROW && bias) bvc = bias[col];
#pragma unroll
        for (int i = 0; i < 4; ++i) {
          const long rowb = row0 + wr + (i << 4) + cr;
#pragma unroll
          for (int r = 0; r < 4; ++r) {
            float v = acc[i][j][r] * alpha + bvc;
            if (BROW) v += bias[rowb + r];
            const long idx = (rowb + r) * (long)Nout + col;
            if (OBF16) {
              if (ACCUM) v += bf2f(((unsigned short*)Cout)[idx]);
              ((unsigned short*)Cout)[idx] = f2bf(v);
            } else {
              ((float*)Cout)[idx] = v;
            }
          }
        }
      }
    }
  }
}

// ---------------------------------------------------------------------------
__global__ __launch_bounds__(256) void cast_f32_to_bf16(
    const float* __restrict__ in, unsigned short* __restrict__ out, int n) {
  int i = (blockIdx.x * 256 + threadIdx.x) * 4;
  if (i + 3 < n) {
    float4 v = *(const float4*)(in + i);
    ushort4 o;
    o.x = f2bf(v.x); o.y = f2bf(v.y); o.z = f2bf(v.z); o.w = f2bf(v.w);
    *(ushort4*)(out + i) = o;
  }
}

__global__ __launch_bounds__(256) void zero_f32(float* __restrict__ p, int n) {
  int i = blockIdx.x * 256 + threadIdx.x;
  if (i < n) p[i] = 0.f;
}

__global__ __launch_bounds__(256) void cat_bias3(
    const float* __restrict__ a, const float* __restrict__ b,
    const float* __restrict__ c, float* __restrict__ o) {
  int i = blockIdx.x * 256 + threadIdx.x;
  if (i < 1024) o[i] = a[i];
  else if (i < 2048) o[i] = b[i - 1024];
  else if (i < 3072) o[i] = c[i - 2048];
}

__global__ __launch_bounds__(1) void sentinel_kernel(float* __restrict__ out) {
  out[0] = -12345.0f;
}

// in[R][C] fp32 -> out[Cpad][R] bf16, rows C..Cpad-1 zeroed. block (32,8)
__global__ void transpose_f32_to_bf16(const float* __restrict__ in,
                                      unsigned short* __restrict__ out,
                                      int R, int C, int Cpad) {
  __shared__ float tile[32][33];
  int c0 = blockIdx.x * 32, r0 = blockIdx.y * 32;
  int tx = threadIdx.x, ty = threadIdx.y;
  for (int i = ty; i < 32; i += 8) {
    int r = r0 + i, c = c0 + tx;
    tile[i][tx] = (r < R && c < C) ? in[(size_t)r * C + c] : 0.f;
  }
  __syncthreads();
  for (int i = ty; i < 32; i += 8) {
    int oc = c0 + i, orr = r0 + tx;
    if (oc < Cpad && orr < R) out[(size_t)oc * R + orr] = f2bf(tile[tx][i]);
  }
}

// beta = sigmoid(inv_l*sum(av*(Wb0+Wb2)) + sum(xr*(Wb1-Wb2)) + bb)
// u = beta*xr + (1-beta)*av*inv_l   (bf16 out). xr stride 3072, av stride 1024.
__global__ __launch_bounds__(256) void beta_combine(
    const unsigned short* __restrict__ xr, const unsigned short* __restrict__ av,
    const float* __restrict__ l, const float* __restrict__ Wb,
    const float* __restrict__ bb, unsigned short* __restrict__ u) {
  const int row = blockIdx.x;
  const int tid = threadIdx.x;
  const unsigned short* xp = xr + (size_t)row * 3072;
  const unsigned short* ap = av + (size_t)row * Dd;
  const float invl = 1.f / l[row];
  __shared__ float red[8];
  float sa = 0.f, sx = 0.f;
  {
    const int j = tid * 4;
    ushort4 a4 = *(const ushort4*)(ap + j);
    ushort4 x4 = *(const ushort4*)(xp + j);
    float4 w0 = *(const float4*)(Wb + j);
    float4 w1 = *(const float4*)(Wb + Dd + j);
    float4 w2 = *(const float4*)(Wb + 2 * Dd + j);
    sa = bf2f(a4.x) * (w0.x + w2.x) + bf2f(a4.y) * (w0.y + w2.y) +
         bf2f(a4.z) * (w0.z + w2.z) + bf2f(a4.w) * (w0.w + w2.w);
    sx = bf2f(x4.x) * (w1.x - w2.x) + bf2f(x4.y) * (w1.y - w2.y) +
         bf2f(x4.z) * (w1.z - w2.z) + bf2f(x4.w) * (w1.w - w2.w);
  }
  sa = wred_sum(sa);
  sx = wred_sum(sx);
  if ((tid & 63) == 0) {
    red[tid >> 6] = sa;
    red[4 + (tid >> 6)] = sx;
  }
  __syncthreads();
  const float s = (red[0] + red[1] + red[2] + red[3]) * invl +
                  (red[4] + red[5] + red[6] + red[7]) + bb[0];
  const float beta = 1.f / (1.f + __expf(-s));
  unsigned short* up = u + (size_t)row * Dd;
  {
    const int j = tid * 4;
    ushort4 a4 = *(const ushort4*)(ap + j);
    ushort4 x4 = *(const ushort4*)(xp + j);
    ushort4 o;
    o.x = f2bf(beta * bf2f(x4.x) + (1.f - beta) * bf2f(a4.x) * invl);
    o.y = f2bf(beta * bf2f(x4.y) + (1.f - beta) * bf2f(a4.y) * invl);
    o.z = f2bf(beta * bf2f(x4.z) + (1.f - beta) * bf2f(a4.z) * invl);
    o.w = f2bf(beta * bf2f(x4.w) + (1.f - beta) * bf2f(a4.w) * invl);
    *(ushort4*)(up + j) = o;
  }
}

// ---------------------------------------------------------------------------
extern "C" void kernel_launch(void* const* d_in, const int* in_sizes, int n_in,
                              void* d_out, int out_size, void* d_ws, size_t ws_size,
                              hipStream_t stream) {
  (void)in_sizes; (void)n_in; (void)out_size;
  const float* x      = (const float*)d_in[0];
  const float* W_skip = (const float*)d_in[1];
  const float* b_skip = (const float*)d_in[2];
  const float* W_q    = (const float*)d_in[3];
  const float* b_q    = (const float*)d_in[4];
  const float* W_k    = (const float*)d_in[5];
  const float* b_k    = (const float*)d_in[6];
  const float* W_v    = (const float*)d_in[7];
  const float* b_v    = (const float*)d_in[8];
  const float* W_beta = (const float*)d_in[9];
  const float* b_beta = (const float*)d_in[10];
  const float* W_fc   = (const float*)d_in[11];
  const float* b_fc   = (const float*)d_in[12];
  float* out = (float*)d_out;

  char* w = (char*)d_ws;
  size_t off = 0;
  auto take = [&](size_t b) -> void* {
    void* p = w + off;
    off += (b + 255) & ~(size_t)255;
    return p;
  };
  const size_t szND2 = (size_t)Nn * Dd * 2;
  const size_t szDD2 = (size_t)Dd * Dd * 2;
  unsigned short* xb   = (unsigned short*)take(szND2);           // x bf16; reused as ub
  unsigned short* qks  = (unsigned short*)take((size_t)Nn * 3072 * 2);  // [q|k|x_r]
  unsigned short* vtb  = (unsigned short*)take(szND2);           // v^T [D][N]
  unsigned short* avb  = (unsigned short*)take(szND2);           // unnormalized P@V, bf16
  unsigned short* wcat = (unsigned short*)take(3 * szDD2);       // [Wq|Wk|Wskip]^T rows
  unsigned short* wvt  = (unsigned short*)take(szDD2);
  unsigned short* wft  = (unsigned short*)take(szDD2);           // padded 1000->1024
  float* bcat          = (float*)take(3072 * 4);
  unsigned short* Sc   = (unsigned short*)take((size_t)Nn * KCHUNK * 2);
  float* lsum          = (float*)take((size_t)Nn * 4);
  unsigned short* ub   = xb;                                     // overlay (xb dead)

  if (off > ws_size) {  // workspace too small -> unmistakable sentinel
    sentinel_kernel<<<1, 1, 0, stream>>>(out);
    return;
  }

  dim3 tb(32, 8);
  cast_f32_to_bf16<<<Nn * Dd / 1024, 256, 0, stream>>>(x, xb, Nn * Dd);
  transpose_f32_to_bf16<<<dim3(32, 32), tb, 0, stream>>>(W_q, wcat, Dd, Dd, Dd);
  transpose_f32_to_bf16<<<dim3(32, 32), tb, 0, stream>>>(W_k, wcat + (size_t)Dd * Dd, Dd, Dd, Dd);
  transpose_f32_to_bf16<<<dim3(32, 32), tb, 0, stream>>>(W_skip, wcat + (size_t)2 * Dd * Dd, Dd, Dd, Dd);
  transpose_f32_to_bf16<<<dim3(32, 32), tb, 0, stream>>>(W_v, wvt, Dd, Dd, Dd);
  transpose_f32_to_bf16<<<dim3(32, 32), tb, 0, stream>>>(W_fc, wft, Dd, Cc_, 1024);
  cat_bias3<<<12, 256, 0, stream>>>(b_q, b_k, b_skip, bcat);

  // fused q|k|x_r projection: [8192][3072]
  gemm_bt<1,0,0,0><<<dim3(64, 24), 256, 0, stream>>>(
      xb, wcat, bcat, qks, Dd, 3072, Dd, Dd, 1.f, nullptr);
  // v^T = W_v^T @ x^T + b_v (bias per row): [1024][8192]
  gemm_bt<1,0,0,1><<<dim3(8, 64), 256, 0, stream>>>(
      wvt, xb, b_v, vtb, Dd, Nn, Dd, Dd, 1.f, nullptr);

  zero_f32<<<Nn / 256, 256, 0, stream>>>(lsum, Nn);

  // chunked attention over keys; no-max softmax (|scores/32| <~ 3, fp32-safe)
  for (int c = 0; c < Nn / KCHUNK; ++c) {
    const unsigned short* kc = qks + (size_t)c * KCHUNK * 3072 + 1024;
    const unsigned short* vc = vtb + (size_t)c * KCHUNK;
    // P_c = exp(q @ k_c^T / 32) bf16 + fused row-sums into lsum
    gemm_bt<1,1,0,0><<<dim3(64, KCHUNK / 128), 256, 0, stream>>>(
        qks, kc, nullptr, Sc, Dd, KCHUNK, 3072, 3072, 0.03125f, lsum);
    // avb (+)= P_c @ v_c  (bf16 accumulate)
    if (c == 0)
      gemm_bt<1,0,0,0><<<dim3(64, 8), 256, 0, stream>>>(
          Sc, vc, nullptr, avb, KCHUNK, Dd, KCHUNK, Nn, 1.f, nullptr);
    else
      gemm_bt<1,0,1,0><<<dim3(64, 8), 256, 0, stream>>>(
          Sc, vc, nullptr, avb, KCHUNK, Dd, KCHUNK, Nn, 1.f, nullptr);
  }

  beta_combine<<<Nn, 256, 0, stream>>>(qks + 2048, avb, lsum, W_beta, b_beta, ub);

  gemm_bt<0,0,0,0><<<dim3(64, 8), 256, 0, stream>>>(
      ub, wft, b_fc, out, Dd, Cc_, Dd, Dd, 1.f, nullptr);
}

// Round 5
// 421.627 us; speedup vs baseline: 1.6677x; 1.3359x over previous
//
#include <hip/hip_runtime.h>
#include <stdint.h>

#define Nn 8192
#define Dd 1024
#define Cc_ 1000

typedef __bf16 bf16x8 __attribute__((ext_vector_type(8)));
typedef float f32x4 __attribute__((ext_vector_type(4)));
typedef int i32x4 __attribute__((ext_vector_type(4)));
typedef int i32x8 __attribute__((ext_vector_type(8)));
typedef const __attribute__((address_space(1))) void* gas1_t;
typedef __attribute__((address_space(3))) void* las3_t;

__device__ __forceinline__ unsigned short f2bf(float f) {
  unsigned u = __float_as_uint(f);
  u = (u + 0x7fffu + ((u >> 16) & 1u)) >> 16;  // RNE
  return (unsigned short)u;
}
__device__ __forceinline__ float bf2f(unsigned short h) {
  return __uint_as_float(((unsigned)h) << 16);
}
__device__ __forceinline__ unsigned char f2fp8(float v) {
  int p = __builtin_amdgcn_cvt_pk_fp8_f32(v, v, 0, false);  // OCP e4m3 on gfx950
  return (unsigned char)(p & 0xff);
}
__device__ __forceinline__ void cp16(const void* g, void* l) {
  __builtin_amdgcn_global_load_lds((gas1_t)g, (las3_t)l, 16, 0, 0);
}
__device__ __forceinline__ float wred_sum(float v) {
#pragma unroll
  for (int m = 32; m; m >>= 1) v += __shfl_xor(v, m, 64);
  return v;
}

// ---------------------------------------------------------------------------
// MX-fp8 GEMM: C = alpha*(A[M][K] @ Bt[*][K]^T) (+bias) (exp+rowsum)
// mfma_scale_f32_16x16x128_f8f6f4 with unit scales (0x7F e8m0 = 1.0) -> 2x
// bf16 MFMA rate (m148: 1628 TF). BK=128: LDS tile 128 rows x 128 B, 16B-unit
// XOR swizzle phys_unit = u ^ (row&7) -> wave-contiguous lane*16 staging and
// evenly-spread b128 frag reads. A-frag: lane m=lane&15, k=(lane>>4)*32+0..31.
// Grid (M/128, ceil(Nout/128)); K%128==0; Bt needs ceil128(Nout) valid rows.
// ---------------------------------------------------------------------------
template <int OFP8, int ER, int BROW>
__global__ __launch_bounds__(256, 3) void gemm_mx(
    const unsigned char* __restrict__ A,
    const unsigned char* __restrict__ Bt,
    const float* __restrict__ bias,
    void* __restrict__ Cout,
    int K, int Nout, int lda, int ldb, float alpha,
    float* __restrict__ lsum) {
  __shared__ __attribute__((aligned(16))) unsigned char sA[16384];
  __shared__ __attribute__((aligned(16))) unsigned char sB[16384];

  const int tid = threadIdx.x;
  const int lane = tid & 63;
  const int wave = tid >> 6;
  const int wr = (wave >> 1) << 6;
  const int wc = (wave & 1) << 6;
  const long row0 = (long)blockIdx.x << 7;
  const long col0 = (long)blockIdx.y << 7;

  // staging: chunk c = wave*4+s covers LDS bytes [c*1024,c*1024+1024) =
  // rows c*8..c*8+7 (128 B each). lane l -> phys row c*8+(l>>3), unit l&7;
  // logical unit u = (l&7) ^ (row&7).
  const unsigned char* gA[4];
  const unsigned char* gB[4];
  unsigned char* lA[4];
  unsigned char* lB[4];
#pragma unroll
  for (int s = 0; s < 4; ++s) {
    const int c = (wave << 2) + s;
    const int prow = (c << 3) + (lane >> 3);
    const int u = (lane & 7) ^ (prow & 7);
    gA[s] = A + (row0 + prow) * (long)lda + u * 16;
    gB[s] = Bt + (col0 + prow) * (long)ldb + u * 16;
    lA[s] = &sA[c << 10];
    lB[s] = &sB[c << 10];
  }

  f32x4 acc[4][4] = {};

  const int m_ = lane & 15;
  const int q_ = lane >> 4;
  const int u0 = (((q_ << 1) ^ (m_ & 7)) << 4);  // byte offset of logical unit 2q
  const int u1 = u0 ^ 16;                         // logical unit 2q+1
  const int am = wr + m_;
  const int bn = wc + m_;

  for (int k0 = 0; k0 < K; k0 += 128) {
    __syncthreads();  // prior iter's LDS reads done
#pragma unroll
    for (int s = 0; s < 4; ++s) {
      cp16(gA[s], lA[s]);
      cp16(gB[s], lB[s]);
      gA[s] += 128;
      gB[s] += 128;
    }
    __syncthreads();  // staging visible

    i32x8 af[4], bfr[4];
#pragma unroll
    for (int i = 0; i < 4; ++i) {
      const int rb = (am + (i << 4)) << 7;
      i32x4 lo = *(const i32x4*)&sA[rb + u0];
      i32x4 hi = *(const i32x4*)&sA[rb + u1];
      af[i] = __builtin_shufflevector(lo, hi, 0, 1, 2, 3, 4, 5, 6, 7);
    }
#pragma unroll
    for (int j = 0; j < 4; ++j) {
      const int rb = (bn + (j << 4)) << 7;
      i32x4 lo = *(const i32x4*)&sB[rb + u0];
      i32x4 hi = *(const i32x4*)&sB[rb + u1];
      bfr[j] = __builtin_shufflevector(lo, hi, 0, 1, 2, 3, 4, 5, 6, 7);
    }
#pragma unroll
    for (int i = 0; i < 4; ++i)
#pragma unroll
      for (int j = 0; j < 4; ++j)
        acc[i][j] = __builtin_amdgcn_mfma_scale_f32_16x16x128_f8f6f4(
            af[i], bfr[j], acc[i][j], 0, 0, 0, 0x7f7f7f7f, 0, 0x7f7f7f7f);
  }

  // C/D layout: col = lane&15, row = (lane>>4)*4 + reg   [m89-verified]
  const int cr = (lane >> 4) << 2;
  const int ccol = lane & 15;
  if (ER) {
    // exp + fp8 store + fused row-sum (full tiles only)
    float rs[4][4];
#pragma unroll
    for (int i = 0; i < 4; ++i)
#pragma unroll
      for (int r = 0; r < 4; ++r) rs[i][r] = 0.f;
#pragma unroll
    for (int j = 0; j < 4; ++j) {
      const long col = col0 + wc + (j << 4) + ccol;
#pragma unroll
      for (int i = 0; i < 4; ++i) {
        const long rowb = row0 + wr + (i << 4) + cr;
#pragma unroll
        for (int r = 0; r < 4; ++r) {
          float v = __expf(acc[i][j][r] * alpha);
          rs[i][r] += v;
          ((unsigned char*)Cout)[(rowb + r) * (long)Nout + col] = f2fp8(v);
        }
      }
    }
#pragma unroll
    for (int i = 0; i < 4; ++i)
#pragma unroll
      for (int r = 0; r < 4; ++r) {
        float s = rs[i][r];
#pragma unroll
        for (int m = 1; m < 16; m <<= 1) s += __shfl_xor(s, m, 64);
        if (ccol == 0)
          atomicAdd(&lsum[row0 + wr + (i << 4) + cr + r], s);
      }
  } else {
#pragma unroll
    for (int j = 0; j < 4; ++j) {
      const long col = col0 + wc + (j << 4) + ccol;
      if (col < Nout) {
        float bvc = 0.f;
        if (!BROW && bias) bvc = bias[col];
#pragma unroll
        for (int i = 0; i < 4; ++i) {
          const long rowb = row0 + wr + (i << 4) + cr;
#pragma unroll
          for (int r = 0; r < 4; ++r) {
            float v = acc[i][j][r] * alpha + bvc;
            if (BROW) v += bias[rowb + r];
            const long idx = (rowb + r) * (long)Nout + col;
            if (OFP8)
              ((unsigned char*)Cout)[idx] = f2fp8(v);
            else
              ((float*)Cout)[idx] = v;
          }
        }
      }
    }
  }
}

// ---------------------------------------------------------------------------
// bf16 GEMM (x_r projection and final FC): round-3's verified kernel.
// ---------------------------------------------------------------------------
template <int OBF16>
__global__ __launch_bounds__(256, 4) void gemm_bt(
    const unsigned short* __restrict__ A,
    const unsigned short* __restrict__ Bt,
    const float* __restrict__ bias,
    void* __restrict__ Cout,
    int K, int Nout, int lda, int ldb, float alpha) {
  __shared__ __attribute__((aligned(16))) unsigned short sA[8192];
  __shared__ __attribute__((aligned(16))) unsigned short sB[8192];

  const int tid = threadIdx.x;
  const int lane = tid & 63;
  const int wave = tid >> 6;
  const int wr = (wave >> 1) << 6;
  const int wc = (wave & 1) << 6;
  const long row0 = (long)blockIdx.x << 7;
  const long col0 = (long)blockIdx.y << 7;

  const int srow = (wave << 4) + (lane >> 2);
  const int sq = (lane & 3) ^ ((lane >> 3) & 3);
  const unsigned short* ga1 = A + (row0 + srow) * lda + sq * 8;
  const unsigned short* ga2 = ga1 + (long)64 * lda;
  const unsigned short* gb1 = Bt + (col0 + srow) * ldb + sq * 8;
  const unsigned short* gb2 = gb1 + (long)64 * ldb;
  unsigned short* la1 = &sA[wave * 512];
  unsigned short* la2 = &sA[2048 + wave * 512];
  unsigned short* lb1 = &sB[wave * 512];
  unsigned short* lb2 = &sB[2048 + wave * 512];

  f32x4 acc[4][4] = {};

  const int fq = ((lane >> 4) ^ ((lane >> 1) & 3)) << 3;
  const int am = wr + (lane & 15);
  const int bn = wc + (lane & 15);

  for (int k0 = 0; k0 < K; k0 += 64) {
    __syncthreads();
    cp16(ga1, la1);             cp16(ga2, la2);
    cp16(ga1 + 32, la1 + 4096); cp16(ga2 + 32, la2 + 4096);
    cp16(gb1, lb1);             cp16(gb2, lb2);
    cp16(gb1 + 32, lb1 + 4096); cp16(gb2 + 32, lb2 + 4096);
    ga1 += 64; ga2 += 64; gb1 += 64; gb2 += 64;
    __syncthreads();

#pragma unroll
    for (int h = 0; h < 2; ++h) {
      const unsigned short* bA = &sA[h << 12];
      const unsigned short* bB = &sB[h << 12];
      bf16x8 af[4], bfr[4];
#pragma unroll
      for (int i = 0; i < 4; ++i)
        af[i] = *(const bf16x8*)&bA[((am + (i << 4)) << 5) + fq];
#pragma unroll
      for (int j = 0; j < 4; ++j)
        bfr[j] = *(const bf16x8*)&bB[((bn + (j << 4)) << 5) + fq];
#pragma unroll
      for (int i = 0; i < 4; ++i)
#pragma unroll
        for (int j = 0; j < 4; ++j)
          acc[i][j] = __builtin_amdgcn_mfma_f32_16x16x32_bf16(af[i], bfr[j], acc[i][j], 0, 0, 0);
    }
  }

  const int cr = (lane >> 4) << 2;
  const int ccol = lane & 15;
#pragma unroll
  for (int j = 0; j < 4; ++j) {
    const long col = col0 + wc + (j << 4) + ccol;
    if (col < Nout) {
      const float bvc = bias ? bias[col] : 0.f;
#pragma unroll
      for (int i = 0; i < 4; ++i) {
        const long rowb = row0 + wr + (i << 4) + cr;
#pragma unroll
        for (int r = 0; r < 4; ++r) {
          float v = acc[i][j][r] * alpha + bvc;
          const long idx = (rowb + r) * (long)Nout + col;
          if (OBF16)
            ((unsigned short*)Cout)[idx] = f2bf(v);
          else
            ((float*)Cout)[idx] = v;
        }
      }
    }
  }
}

// ---------------------------------------------------------------------------
__global__ __launch_bounds__(256) void cast_f32_to_bf16(
    const float* __restrict__ in, unsigned short* __restrict__ out, int n) {
  int i = (blockIdx.x * 256 + threadIdx.x) * 4;
  if (i + 3 < n) {
    float4 v = *(const float4*)(in + i);
    ushort4 o;
    o.x = f2bf(v.x); o.y = f2bf(v.y); o.z = f2bf(v.z); o.w = f2bf(v.w);
    *(ushort4*)(out + i) = o;
  }
}

__global__ __launch_bounds__(256) void cast_f32_to_fp8(
    const float* __restrict__ in, unsigned char* __restrict__ out, int n) {
  int i = (blockIdx.x * 256 + threadIdx.x) * 4;
  if (i + 3 < n) {
    float4 v = *(const float4*)(in + i);
    int p = __builtin_amdgcn_cvt_pk_fp8_f32(v.x, v.y, 0, false);
    p = __builtin_amdgcn_cvt_pk_fp8_f32(v.z, v.w, p, true);
    *(int*)(out + i) = p;
  }
}

__global__ __launch_bounds__(256) void zero_f32(float* __restrict__ p, int n) {
  int i = blockIdx.x * 256 + threadIdx.x;
  if (i < n) p[i] = 0.f;
}

__global__ __launch_bounds__(256) void cat_bias2(
    const float* __restrict__ a, const float* __restrict__ b,
    float* __restrict__ o) {
  int i = blockIdx.x * 256 + threadIdx.x;
  if (i < 1024) o[i] = a[i];
  else if (i < 2048) o[i] = b[i - 1024];
}

__global__ __launch_bounds__(1) void sentinel_kernel(float* __restrict__ out) {
  out[0] = -12345.0f;
}

// in[R][C] fp32 -> out[Cpad][R] bf16, rows C..Cpad-1 zeroed. block (32,8)
__global__ void transpose_f32_to_bf16(const float* __restrict__ in,
                                      unsigned short* __restrict__ out,
                                      int R, int C, int Cpad) {
  __shared__ float tile[32][33];
  int c0 = blockIdx.x * 32, r0 = blockIdx.y * 32;
  int tx = threadIdx.x, ty = threadIdx.y;
  for (int i = ty; i < 32; i += 8) {
    int r = r0 + i, c = c0 + tx;
    tile[i][tx] = (r < R && c < C) ? in[(size_t)r * C + c] : 0.f;
  }
  __syncthreads();
  for (int i = ty; i < 32; i += 8) {
    int oc = c0 + i, orr = r0 + tx;
    if (oc < Cpad && orr < R) out[(size_t)oc * R + orr] = f2bf(tile[tx][i]);
  }
}

// in[R][C] fp32 -> out[C][R] fp8. R,C multiples of 32. block (32,8)
__global__ void transpose_f32_to_fp8(const float* __restrict__ in,
                                     unsigned char* __restrict__ out,
                                     int R, int C) {
  __shared__ float tile[32][33];
  int c0 = blockIdx.x * 32, r0 = blockIdx.y * 32;
  int tx = threadIdx.x, ty = threadIdx.y;
  for (int i = ty; i < 32; i += 8)
    tile[i][tx] = in[(size_t)(r0 + i) * C + (c0 + tx)];
  __syncthreads();
  for (int i = ty; i < 32; i += 8)
    out[(size_t)(c0 + i) * R + (r0 + tx)] = f2fp8(tile[tx][i]);
}

// beta = sigmoid(inv_l*sum(av*(Wb0+Wb2)) + sum(xr*(Wb1-Wb2)) + bb)
// u = beta*xr + (1-beta)*av*inv_l   (bf16 out). xr bf16, av fp32, both ld 1024.
__global__ __launch_bounds__(256) void beta_combine(
    const unsigned short* __restrict__ xr, const float* __restrict__ av,
    const float* __restrict__ l, const float* __restrict__ Wb,
    const float* __restrict__ bb, unsigned short* __restrict__ u) {
  const int row = blockIdx.x;
  const int tid = threadIdx.x;
  const unsigned short* xp = xr + (size_t)row * Dd;
  const float* ap = av + (size_t)row * Dd;
  const float invl = 1.f / l[row];
  __shared__ float red[8];
  float sa, sx;
  const int j = tid * 4;
  float4 a4 = *(const float4*)(ap + j);
  ushort4 x4 = *(const ushort4*)(xp + j);
  {
    float4 w0 = *(const float4*)(Wb + j);
    float4 w1 = *(const float4*)(Wb + Dd + j);
    float4 w2 = *(const float4*)(Wb + 2 * Dd + j);
    sa = a4.x * (w0.x + w2.x) + a4.y * (w0.y + w2.y) +
         a4.z * (w0.z + w2.z) + a4.w * (w0.w + w2.w);
    sx = bf2f(x4.x) * (w1.x - w2.x) + bf2f(x4.y) * (w1.y - w2.y) +
         bf2f(x4.z) * (w1.z - w2.z) + bf2f(x4.w) * (w1.w - w2.w);
  }
  sa = wred_sum(sa);
  sx = wred_sum(sx);
  if ((tid & 63) == 0) {
    red[tid >> 6] = sa;
    red[4 + (tid >> 6)] = sx;
  }
  __syncthreads();
  const float s = (red[0] + red[1] + red[2] + red[3]) * invl +
                  (red[4] + red[5] + red[6] + red[7]) + bb[0];
  const float beta = 1.f / (1.f + __expf(-s));
  unsigned short* up = u + (size_t)row * Dd;
  ushort4 o;
  o.x = f2bf(beta * bf2f(x4.x) + (1.f - beta) * a4.x * invl);
  o.y = f2bf(beta * bf2f(x4.y) + (1.f - beta) * a4.y * invl);
  o.z = f2bf(beta * bf2f(x4.z) + (1.f - beta) * a4.z * invl);
  o.w = f2bf(beta * bf2f(x4.w) + (1.f - beta) * a4.w * invl);
  *(ushort4*)(up + j) = o;
}

// ---------------------------------------------------------------------------
extern "C" void kernel_launch(void* const* d_in, const int* in_sizes, int n_in,
                              void* d_out, int out_size, void* d_ws, size_t ws_size,
                              hipStream_t stream) {
  (void)in_sizes; (void)n_in; (void)out_size;
  const float* x      = (const float*)d_in[0];
  const float* W_skip = (const float*)d_in[1];
  const float* b_skip = (const float*)d_in[2];
  const float* W_q    = (const float*)d_in[3];
  const float* b_q    = (const float*)d_in[4];
  const float* W_k    = (const float*)d_in[5];
  const float* b_k    = (const float*)d_in[6];
  const float* W_v    = (const float*)d_in[7];
  const float* b_v    = (const float*)d_in[8];
  const float* W_beta = (const float*)d_in[9];
  const float* b_beta = (const float*)d_in[10];
  const float* W_fc   = (const float*)d_in[11];
  const float* b_fc   = (const float*)d_in[12];
  float* out = (float*)d_out;

  char* w = (char*)d_ws;
  size_t off = 0;
  auto take = [&](size_t b) -> void* {
    void* p = w + off;
    off += (b + 255) & ~(size_t)255;
    return p;
  };
  const size_t szND2 = (size_t)Nn * Dd * 2;
  unsigned short* xb   = (unsigned short*)take(szND2);            // x bf16 (-> ub)
  unsigned char*  xf8  = (unsigned char*)take((size_t)Nn * Dd);   // x fp8
  unsigned char*  qkf  = (unsigned char*)take((size_t)Nn * 2048); // [q|k] fp8
  unsigned short* xrb  = (unsigned short*)take(szND2);            // x_r bf16
  unsigned char*  vtf  = (unsigned char*)take((size_t)Dd * Nn);   // v^T fp8 [D][N]
  float*          avf  = (float*)take((size_t)Nn * Dd * 4);       // unnorm P@V fp32
  unsigned char*  wqkt = (unsigned char*)take((size_t)2048 * Dd); // [Wq|Wk]^T fp8
  unsigned char*  wvt8 = (unsigned char*)take((size_t)Dd * Dd);   // Wv^T fp8
  unsigned short* wst  = (unsigned short*)take((size_t)Dd * Dd * 2);
  unsigned short* wft  = (unsigned short*)take((size_t)Dd * Dd * 2);  // 1000->1024
  unsigned char*  Sc   = (unsigned char*)take((size_t)Nn * Nn);   // P fp8 [N][N]
  float*          lsum = (float*)take((size_t)Nn * 4);
  float*          bqk  = (float*)take(2048 * 4);
  unsigned short* ub   = xb;                                      // overlay

  if (off > ws_size) {  // workspace too small -> unmistakable sentinel
    sentinel_kernel<<<1, 1, 0, stream>>>(out);
    return;
  }

  dim3 tb(32, 8);
  cast_f32_to_bf16<<<Nn * Dd / 1024, 256, 0, stream>>>(x, xb, Nn * Dd);
  cast_f32_to_fp8<<<Nn * Dd / 1024, 256, 0, stream>>>(x, xf8, Nn * Dd);
  transpose_f32_to_fp8<<<dim3(32, 32), tb, 0, stream>>>(W_q, wqkt, Dd, Dd);
  transpose_f32_to_fp8<<<dim3(32, 32), tb, 0, stream>>>(W_k, wqkt + (size_t)Dd * Dd, Dd, Dd);
  transpose_f32_to_fp8<<<dim3(32, 32), tb, 0, stream>>>(W_v, wvt8, Dd, Dd);
  transpose_f32_to_bf16<<<dim3(32, 32), tb, 0, stream>>>(W_skip, wst, Dd, Dd, Dd);
  transpose_f32_to_bf16<<<dim3(32, 32), tb, 0, stream>>>(W_fc, wft, Dd, Cc_, 1024);
  cat_bias2<<<8, 256, 0, stream>>>(b_q, b_k, bqk);
  zero_f32<<<Nn / 256, 256, 0, stream>>>(lsum, Nn);

  // [q|k] = x @ [Wq|Wk] + bias   (fp8 in/out): [8192][2048]
  gemm_mx<1, 0, 0><<<dim3(64, 16), 256, 0, stream>>>(
      xf8, wqkt, bqk, qkf, Dd, 2048, Dd, Dd, 1.f, nullptr);
  // v^T = Wv^T @ x^T + b_v (bias per row): [1024][8192] fp8
  gemm_mx<1, 0, 1><<<dim3(8, 64), 256, 0, stream>>>(
      wvt8, xf8, b_v, vtf, Dd, Nn, Dd, Dd, 1.f, nullptr);
  // x_r = x @ W_skip + b_skip  (bf16): [8192][1024]
  gemm_bt<1><<<dim3(64, 8), 256, 0, stream>>>(
      xb, wst, b_skip, xrb, Dd, Dd, Dd, Dd, 1.f);

  // P = exp(q @ k^T / 32)  (fp8 out, fused row-sums; no-max softmax is safe:
  // |scores/32| <~ 3 -> exp in [0.05, 30], well within e4m3 range)
  gemm_mx<1, 1, 0><<<dim3(64, 64), 256, 0, stream>>>(
      qkf, qkf + 1024, nullptr, Sc, Dd, Nn, 2048, 2048, 0.03125f, lsum);
  // av = P @ v  (fp32 out): [8192][1024], K=8192
  gemm_mx<0, 0, 0><<<dim3(64, 8), 256, 0, stream>>>(
      Sc, vtf, nullptr, avf, Nn, Dd, Nn, Nn, 1.f, nullptr);

  beta_combine<<<Nn, 256, 0, stream>>>(xrb, avf, lsum, W_beta, b_beta, ub);

  gemm_bt<0><<<dim3(64, 8), 256, 0, stream>>>(
      ub, wft, b_fc, out, Dd, Cc_, Dd, Dd, 1.f);
}

// Round 6
// 419.770 us; speedup vs baseline: 1.6751x; 1.0044x over previous
//
#include <hip/hip_runtime.h>
#include <stdint.h>

#define Nn 8192
#define Dd 1024
#define Cc_ 1000

typedef __bf16 bf16x8 __attribute__((ext_vector_type(8)));
typedef float f32x4 __attribute__((ext_vector_type(4)));
typedef int i32x4 __attribute__((ext_vector_type(4)));
typedef int i32x8 __attribute__((ext_vector_type(8)));
typedef const __attribute__((address_space(1))) void* gas1_t;
typedef __attribute__((address_space(3))) void* las3_t;

__device__ __forceinline__ unsigned short f2bf(float f) {
  unsigned u = __float_as_uint(f);
  u = (u + 0x7fffu + ((u >> 16) & 1u)) >> 16;  // RNE
  return (unsigned short)u;
}
__device__ __forceinline__ float bf2f(unsigned short h) {
  return __uint_as_float(((unsigned)h) << 16);
}
__device__ __forceinline__ unsigned char f2fp8(float v) {
  int p = __builtin_amdgcn_cvt_pk_fp8_f32(v, v, 0, false);  // OCP e4m3 on gfx950
  return (unsigned char)(p & 0xff);
}
__device__ __forceinline__ void cp16(const void* g, void* l) {
  __builtin_amdgcn_global_load_lds((gas1_t)g, (las3_t)l, 16, 0, 0);
}
__device__ __forceinline__ float wred_sum(float v) {
#pragma unroll
  for (int m = 32; m; m >>= 1) v += __shfl_xor(v, m, 64);
  return v;
}

// ---------------------------------------------------------------------------
// MX-fp8 GEMM: C = alpha*(A[M][K] @ Bt[*][K]^T) (+bias) (exp+rowsum)
// mfma_scale_f32_16x16x128_f8f6f4, unit scales (0x7F e8m0 = 1.0).
// BK=128. LDS layout = bf16-kernel geometry (measured 0 conflicts) applied
// to fp8: each 128-B logical row r stored as two 64-B HALF-ROWS at
// hr = 2r + (h ^ (r&1)) (bank-base alternates with lane in frag reads) with
// 16-B units swizzled p = u2 ^ ((r>>1)&3) (position rotates per lane pair).
// Round-4's 128-B-row layout had all rows bank-base 0 -> exactly 16 conflict
// cycles per wave ds_read_b128 (2^23/dispatch, 3x LDS penalty).
// Staging stays wave-contiguous lane*16 for global_load_lds (verified
// inverse-bijection with frag-read decode).
// Grid (M/128, ceil(Nout/128)); K%128==0; Bt needs ceil128(Nout) valid rows.
// ---------------------------------------------------------------------------
template <int OFP8, int ER, int BROW>
__global__ __launch_bounds__(256, 3) void gemm_mx(
    const unsigned char* __restrict__ A,
    const unsigned char* __restrict__ Bt,
    const float* __restrict__ bias,
    void* __restrict__ Cout,
    int K, int Nout, int lda, int ldb, float alpha,
    float* __restrict__ lsum) {
  __shared__ __attribute__((aligned(16))) unsigned char sA[16384];
  __shared__ __attribute__((aligned(16))) unsigned char sB[16384];

  const int tid = threadIdx.x;
  const int lane = tid & 63;
  const int wave = tid >> 6;
  const int wr = (wave >> 1) << 6;
  const int wc = (wave & 1) << 6;
  const long row0 = (long)blockIdx.x << 7;
  const long col0 = (long)blockIdx.y << 7;

  // staging: chunk c = wave*4+s covers LDS bytes [c*1024,c*1024+1024) =
  // half-rows 16c..16c+15. Lane l writes 16 B at l*16 -> physical
  // (hr = 16c + (l>>2), pos = l&3), which holds logical
  // row r = 8c + (l>>3), half h = ((l>>2)^(l>>3))&1, unit u2 = (l&3)^((l>>4)&3).
  const unsigned char* gA[4];
  const unsigned char* gB[4];
  unsigned char* lA[4];
  unsigned char* lB[4];
  {
    const int r_ = (lane >> 3);
    const int go = ((((lane >> 2) ^ (lane >> 3)) & 1) << 6) +
                   (((lane & 3) ^ ((lane >> 4) & 3)) << 4);
#pragma unroll
    for (int s = 0; s < 4; ++s) {
      const int c = (wave << 2) + s;
      gA[s] = A + (row0 + (c << 3) + r_) * (long)lda + go;
      gB[s] = Bt + (col0 + (c << 3) + r_) * (long)ldb + go;
      lA[s] = &sA[c << 10];
      lB[s] = &sB[c << 10];
    }
  }

  f32x4 acc[4][4] = {};

  // frag read: lane (m,q) reads logical row r=w+m+16i, units 2q (lo), 2q+1 (hi):
  // byte = 128*r + 64*((q>>1)^(m&1)) + 16*(((q&1)<<1)^((m>>1)&3)); hi = lo^16.
  const int m_ = lane & 15;
  const int q_ = lane >> 4;
  const int fo = ((((q_ >> 1) ^ m_) & 1) << 6) +
                 (((q_ & 1) << 1) ^ ((m_ >> 1) & 3)) << 4;
  const int aoffA = ((wr + m_) << 7) + ((((q_ >> 1) ^ m_) & 1) << 6) +
                    (((((q_ & 1) << 1) ^ ((m_ >> 1) & 3))) << 4);
  const int aoffB = ((wc + m_) << 7) + ((((q_ >> 1) ^ m_) & 1) << 6) +
                    (((((q_ & 1) << 1) ^ ((m_ >> 1) & 3))) << 4);
  (void)fo;

  for (int k0 = 0; k0 < K; k0 += 128) {
    __syncthreads();  // prior iter's LDS reads done
#pragma unroll
    for (int s = 0; s < 4; ++s) {
      cp16(gA[s], lA[s]);
      cp16(gB[s], lB[s]);
      gA[s] += 128;
      gB[s] += 128;
    }
    __syncthreads();  // staging visible

    i32x8 af[4], bfr[4];
#pragma unroll
    for (int i = 0; i < 4; ++i) {
      const int ba = aoffA + (i << 11);
      i32x4 lo = *(const i32x4*)&sA[ba];
      i32x4 hi = *(const i32x4*)&sA[ba ^ 16];
      af[i] = __builtin_shufflevector(lo, hi, 0, 1, 2, 3, 4, 5, 6, 7);
    }
#pragma unroll
    for (int j = 0; j < 4; ++j) {
      const int bb = aoffB + (j << 11);
      i32x4 lo = *(const i32x4*)&sB[bb];
      i32x4 hi = *(const i32x4*)&sB[bb ^ 16];
      bfr[j] = __builtin_shufflevector(lo, hi, 0, 1, 2, 3, 4, 5, 6, 7);
    }
#pragma unroll
    for (int i = 0; i < 4; ++i)
#pragma unroll
      for (int j = 0; j < 4; ++j)
        acc[i][j] = __builtin_amdgcn_mfma_scale_f32_16x16x128_f8f6f4(
            af[i], bfr[j], acc[i][j], 0, 0, 0, 0x7f7f7f7f, 0, 0x7f7f7f7f);
  }

  // C/D layout: col = lane&15, row = (lane>>4)*4 + reg   [m89-verified]
  const int cr = (lane >> 4) << 2;
  const int ccol = lane & 15;
  if (ER) {
    // exp + fp8 store + fused row-sum (full tiles only)
    float rs[4][4];
#pragma unroll
    for (int i = 0; i < 4; ++i)
#pragma unroll
      for (int r = 0; r < 4; ++r) rs[i][r] = 0.f;
#pragma unroll
    for (int j = 0; j < 4; ++j) {
      const long col = col0 + wc + (j << 4) + ccol;
#pragma unroll
      for (int i = 0; i < 4; ++i) {
        const long rowb = row0 + wr + (i << 4) + cr;
#pragma unroll
        for (int r = 0; r < 4; ++r) {
          float v = __expf(acc[i][j][r] * alpha);
          rs[i][r] += v;
          ((unsigned char*)Cout)[(rowb + r) * (long)Nout + col] = f2fp8(v);
        }
      }
    }
#pragma unroll
    for (int i = 0; i < 4; ++i)
#pragma unroll
      for (int r = 0; r < 4; ++r) {
        float s = rs[i][r];
#pragma unroll
        for (int m = 1; m < 16; m <<= 1) s += __shfl_xor(s, m, 64);
        if (ccol == 0)
          atomicAdd(&lsum[row0 + wr + (i << 4) + cr + r], s);
      }
  } else {
#pragma unroll
    for (int j = 0; j < 4; ++j) {
      const long col = col0 + wc + (j << 4) + ccol;
      if (col < Nout) {
        float bvc = 0.f;
        if (!BROW && bias) bvc = bias[col];
#pragma unroll
        for (int i = 0; i < 4; ++i) {
          const long rowb = row0 + wr + (i << 4) + cr;
#pragma unroll
          for (int r = 0; r < 4; ++r) {
            float v = acc[i][j][r] * alpha + bvc;
            if (BROW) v += bias[rowb + r];
            const long idx = (rowb + r) * (long)Nout + col;
            if (OFP8)
              ((unsigned char*)Cout)[idx] = f2fp8(v);
            else
              ((float*)Cout)[idx] = v;
          }
        }
      }
    }
  }
}

// ---------------------------------------------------------------------------
// bf16 GEMM (x_r projection and final FC): round-3's verified kernel.
// ---------------------------------------------------------------------------
template <int OBF16>
__global__ __launch_bounds__(256, 4) void gemm_bt(
    const unsigned short* __restrict__ A,
    const unsigned short* __restrict__ Bt,
    const float* __restrict__ bias,
    void* __restrict__ Cout,
    int K, int Nout, int lda, int ldb, float alpha) {
  __shared__ __attribute__((aligned(16))) unsigned short sA[8192];
  __shared__ __attribute__((aligned(16))) unsigned short sB[8192];

  const int tid = threadIdx.x;
  const int lane = tid & 63;
  const int wave = tid >> 6;
  const int wr = (wave >> 1) << 6;
  const int wc = (wave & 1) << 6;
  const long row0 = (long)blockIdx.x << 7;
  const long col0 = (long)blockIdx.y << 7;

  const int srow = (wave << 4) + (lane >> 2);
  const int sq = (lane & 3) ^ ((lane >> 3) & 3);
  const unsigned short* ga1 = A + (row0 + srow) * lda + sq * 8;
  const unsigned short* ga2 = ga1 + (long)64 * lda;
  const unsigned short* gb1 = Bt + (col0 + srow) * ldb + sq * 8;
  const unsigned short* gb2 = gb1 + (long)64 * ldb;
  unsigned short* la1 = &sA[wave * 512];
  unsigned short* la2 = &sA[2048 + wave * 512];
  unsigned short* lb1 = &sB[wave * 512];
  unsigned short* lb2 = &sB[2048 + wave * 512];

  f32x4 acc[4][4] = {};

  const int fq = ((lane >> 4) ^ ((lane >> 1) & 3)) << 3;
  const int am = wr + (lane & 15);
  const int bn = wc + (lane & 15);

  for (int k0 = 0; k0 < K; k0 += 64) {
    __syncthreads();
    cp16(ga1, la1);             cp16(ga2, la2);
    cp16(ga1 + 32, la1 + 4096); cp16(ga2 + 32, la2 + 4096);
    cp16(gb1, lb1);             cp16(gb2, lb2);
    cp16(gb1 + 32, lb1 + 4096); cp16(gb2 + 32, lb2 + 4096);
    ga1 += 64; ga2 += 64; gb1 += 64; gb2 += 64;
    __syncthreads();

#pragma unroll
    for (int h = 0; h < 2; ++h) {
      const unsigned short* bA = &sA[h << 12];
      const unsigned short* bB = &sB[h << 12];
      bf16x8 af[4], bfr[4];
#pragma unroll
      for (int i = 0; i < 4; ++i)
        af[i] = *(const bf16x8*)&bA[((am + (i << 4)) << 5) + fq];
#pragma unroll
      for (int j = 0; j < 4; ++j)
        bfr[j] = *(const bf16x8*)&bB[((bn + (j << 4)) << 5) + fq];
#pragma unroll
      for (int i = 0; i < 4; ++i)
#pragma unroll
        for (int j = 0; j < 4; ++j)
          acc[i][j] = __builtin_amdgcn_mfma_f32_16x16x32_bf16(af[i], bfr[j], acc[i][j], 0, 0, 0);
    }
  }

  const int cr = (lane >> 4) << 2;
  const int ccol = lane & 15;
#pragma unroll
  for (int j = 0; j < 4; ++j) {
    const long col = col0 + wc + (j << 4) + ccol;
    if (col < Nout) {
      const float bvc = bias ? bias[col] : 0.f;
#pragma unroll
      for (int i = 0; i < 4; ++i) {
        const long rowb = row0 + wr + (i << 4) + cr;
#pragma unroll
        for (int r = 0; r < 4; ++r) {
          float v = acc[i][j][r] * alpha + bvc;
          const long idx = (rowb + r) * (long)Nout + col;
          if (OBF16)
            ((unsigned short*)Cout)[idx] = f2bf(v);
          else
            ((float*)Cout)[idx] = v;
        }
      }
    }
  }
}

// ---------------------------------------------------------------------------
__global__ __launch_bounds__(256) void cast_f32_to_bf16(
    const float* __restrict__ in, unsigned short* __restrict__ out, int n) {
  int i = (blockIdx.x * 256 + threadIdx.x) * 4;
  if (i + 3 < n) {
    float4 v = *(const float4*)(in + i);
    ushort4 o;
    o.x = f2bf(v.x); o.y = f2bf(v.y); o.z = f2bf(v.z); o.w = f2bf(v.w);
    *(ushort4*)(out + i) = o;
  }
}

__global__ __launch_bounds__(256) void cast_f32_to_fp8(
    const float* __restrict__ in, unsigned char* __restrict__ out, int n) {
  int i = (blockIdx.x * 256 + threadIdx.x) * 4;
  if (i + 3 < n) {
    float4 v = *(const float4*)(in + i);
    int p = __builtin_amdgcn_cvt_pk_fp8_f32(v.x, v.y, 0, false);
    p = __builtin_amdgcn_cvt_pk_fp8_f32(v.z, v.w, p, true);
    *(int*)(out + i) = p;
  }
}

__global__ __launch_bounds__(256) void zero_f32(float* __restrict__ p, int n) {
  int i = blockIdx.x * 256 + threadIdx.x;
  if (i < n) p[i] = 0.f;
}

__global__ __launch_bounds__(256) void cat_bias2(
    const float* __restrict__ a, const float* __restrict__ b,
    float* __restrict__ o) {
  int i = blockIdx.x * 256 + threadIdx.x;
  if (i < 1024) o[i] = a[i];
  else if (i < 2048) o[i] = b[i - 1024];
}

__global__ __launch_bounds__(1) void sentinel_kernel(float* __restrict__ out) {
  out[0] = -12345.0f;
}

// in[R][C] fp32 -> out[Cpad][R] bf16, rows C..Cpad-1 zeroed. block (32,8)
__global__ void transpose_f32_to_bf16(const float* __restrict__ in,
                                      unsigned short* __restrict__ out,
                                      int R, int C, int Cpad) {
  __shared__ float tile[32][33];
  int c0 = blockIdx.x * 32, r0 = blockIdx.y * 32;
  int tx = threadIdx.x, ty = threadIdx.y;
  for (int i = ty; i < 32; i += 8) {
    int r = r0 + i, c = c0 + tx;
    tile[i][tx] = (r < R && c < C) ? in[(size_t)r * C + c] : 0.f;
  }
  __syncthreads();
  for (int i = ty; i < 32; i += 8) {
    int oc = c0 + i, orr = r0 + tx;
    if (oc < Cpad && orr < R) out[(size_t)oc * R + orr] = f2bf(tile[tx][i]);
  }
}

// in[R][C] fp32 -> out[C][R] fp8. R,C multiples of 32. block (32,8)
__global__ void transpose_f32_to_fp8(const float* __restrict__ in,
                                     unsigned char* __restrict__ out,
                                     int R, int C) {
  __shared__ float tile[32][33];
  int c0 = blockIdx.x * 32, r0 = blockIdx.y * 32;
  int tx = threadIdx.x, ty = threadIdx.y;
  for (int i = ty; i < 32; i += 8)
    tile[i][tx] = in[(size_t)(r0 + i) * C + (c0 + tx)];
  __syncthreads();
  for (int i = ty; i < 32; i += 8)
    out[(size_t)(c0 + i) * R + (r0 + tx)] = f2fp8(tile[tx][i]);
}

// beta = sigmoid(inv_l*sum(av*(Wb0+Wb2)) + sum(xr*(Wb1-Wb2)) + bb)
// u = beta*xr + (1-beta)*av*inv_l   (bf16 out). xr bf16, av fp32, both ld 1024.
__global__ __launch_bounds__(256) void beta_combine(
    const unsigned short* __restrict__ xr, const float* __restrict__ av,
    const float* __restrict__ l, const float* __restrict__ Wb,
    const float* __restrict__ bb, unsigned short* __restrict__ u) {
  const int row = blockIdx.x;
  const int tid = threadIdx.x;
  const unsigned short* xp = xr + (size_t)row * Dd;
  const float* ap = av + (size_t)row * Dd;
  const float invl = 1.f / l[row];
  __shared__ float red[8];
  float sa, sx;
  const int j = tid * 4;
  float4 a4 = *(const float4*)(ap + j);
  ushort4 x4 = *(const ushort4*)(xp + j);
  {
    float4 w0 = *(const float4*)(Wb + j);
    float4 w1 = *(const float4*)(Wb + Dd + j);
    float4 w2 = *(const float4*)(Wb + 2 * Dd + j);
    sa = a4.x * (w0.x + w2.x) + a4.y * (w0.y + w2.y) +
         a4.z * (w0.z + w2.z) + a4.w * (w0.w + w2.w);
    sx = bf2f(x4.x) * (w1.x - w2.x) + bf2f(x4.y) * (w1.y - w2.y) +
         bf2f(x4.z) * (w1.z - w2.z) + bf2f(x4.w) * (w1.w - w2.w);
  }
  sa = wred_sum(sa);
  sx = wred_sum(sx);
  if ((tid & 63) == 0) {
    red[tid >> 6] = sa;
    red[4 + (tid >> 6)] = sx;
  }
  __syncthreads();
  const float s = (red[0] + red[1] + red[2] + red[3]) * invl +
                  (red[4] + red[5] + red[6] + red[7]) + bb[0];
  const float beta = 1.f / (1.f + __expf(-s));
  unsigned short* up = u + (size_t)row * Dd;
  ushort4 o;
  o.x = f2bf(beta * bf2f(x4.x) + (1.f - beta) * a4.x * invl);
  o.y = f2bf(beta * bf2f(x4.y) + (1.f - beta) * a4.y * invl);
  o.z = f2bf(beta * bf2f(x4.z) + (1.f - beta) * a4.z * invl);
  o.w = f2bf(beta * bf2f(x4.w) + (1.f - beta) * a4.w * invl);
  *(ushort4*)(up + j) = o;
}

// ---------------------------------------------------------------------------
extern "C" void kernel_launch(void* const* d_in, const int* in_sizes, int n_in,
                              void* d_out, int out_size, void* d_ws, size_t ws_size,
                              hipStream_t stream) {
  (void)in_sizes; (void)n_in; (void)out_size;
  const float* x      = (const float*)d_in[0];
  const float* W_skip = (const float*)d_in[1];
  const float* b_skip = (const float*)d_in[2];
  const float* W_q    = (const float*)d_in[3];
  const float* b_q    = (const float*)d_in[4];
  const float* W_k    = (const float*)d_in[5];
  const float* b_k    = (const float*)d_in[6];
  const float* W_v    = (const float*)d_in[7];
  const float* b_v    = (const float*)d_in[8];
  const float* W_beta = (const float*)d_in[9];
  const float* b_beta = (const float*)d_in[10];
  const float* W_fc   = (const float*)d_in[11];
  const float* b_fc   = (const float*)d_in[12];
  float* out = (float*)d_out;

  char* w = (char*)d_ws;
  size_t off = 0;
  auto take = [&](size_t b) -> void* {
    void* p = w + off;
    off += (b + 255) & ~(size_t)255;
    return p;
  };
  const size_t szND2 = (size_t)Nn * Dd * 2;
  unsigned short* xb   = (unsigned short*)take(szND2);            // x bf16 (-> ub)
  unsigned char*  xf8  = (unsigned char*)take((size_t)Nn * Dd);   // x fp8
  unsigned char*  qkf  = (unsigned char*)take((size_t)Nn * 2048); // [q|k] fp8
  unsigned short* xrb  = (unsigned short*)take(szND2);            // x_r bf16
  unsigned char*  vtf  = (unsigned char*)take((size_t)Dd * Nn);   // v^T fp8 [D][N]
  float*          avf  = (float*)take((size_t)Nn * Dd * 4);       // unnorm P@V fp32
  unsigned char*  wqkt = (unsigned char*)take((size_t)2048 * Dd); // [Wq|Wk]^T fp8
  unsigned char*  wvt8 = (unsigned char*)take((size_t)Dd * Dd);   // Wv^T fp8
  unsigned short* wst  = (unsigned short*)take((size_t)Dd * Dd * 2);
  unsigned short* wft  = (unsigned short*)take((size_t)Dd * Dd * 2);  // 1000->1024
  unsigned char*  Sc   = (unsigned char*)take((size_t)Nn * Nn);   // P fp8 [N][N]
  float*          lsum = (float*)take((size_t)Nn * 4);
  float*          bqk  = (float*)take(2048 * 4);
  unsigned short* ub   = xb;                                      // overlay

  if (off > ws_size) {  // workspace too small -> unmistakable sentinel
    sentinel_kernel<<<1, 1, 0, stream>>>(out);
    return;
  }

  dim3 tb(32, 8);
  cast_f32_to_bf16<<<Nn * Dd / 1024, 256, 0, stream>>>(x, xb, Nn * Dd);
  cast_f32_to_fp8<<<Nn * Dd / 1024, 256, 0, stream>>>(x, xf8, Nn * Dd);
  transpose_f32_to_fp8<<<dim3(32, 32), tb, 0, stream>>>(W_q, wqkt, Dd, Dd);
  transpose_f32_to_fp8<<<dim3(32, 32), tb, 0, stream>>>(W_k, wqkt + (size_t)Dd * Dd, Dd, Dd);
  transpose_f32_to_fp8<<<dim3(32, 32), tb, 0, stream>>>(W_v, wvt8, Dd, Dd);
  transpose_f32_to_bf16<<<dim3(32, 32), tb, 0, stream>>>(W_skip, wst, Dd, Dd, Dd);
  transpose_f32_to_bf16<<<dim3(32, 32), tb, 0, stream>>>(W_fc, wft, Dd, Cc_, 1024);
  cat_bias2<<<8, 256, 0, stream>>>(b_q, b_k, bqk);
  zero_f32<<<Nn / 256, 256, 0, stream>>>(lsum, Nn);

  // [q|k] = x @ [Wq|Wk] + bias   (fp8 in/out): [8192][2048]
  gemm_mx<1, 0, 0><<<dim3(64, 16), 256, 0, stream>>>(
      xf8, wqkt, bqk, qkf, Dd, 2048, Dd, Dd, 1.f, nullptr);
  // v^T = Wv^T @ x^T + b_v (bias per row): [1024][8192] fp8
  gemm_mx<1, 0, 1><<<dim3(8, 64), 256, 0, stream>>>(
      wvt8, xf8, b_v, vtf, Dd, Nn, Dd, Dd, 1.f, nullptr);
  // x_r = x @ W_skip + b_skip  (bf16): [8192][1024]
  gemm_bt<1><<<dim3(64, 8), 256, 0, stream>>>(
      xb, wst, b_skip, xrb, Dd, Dd, Dd, Dd, 1.f);

  // P = exp(q @ k^T / 32)  (fp8 out, fused row-sums; no-max softmax is safe:
  // |scores/32| <~ 3 -> exp in [0.05, 30], well within e4m3 range)
  gemm_mx<1, 1, 0><<<dim3(64, 64), 256, 0, stream>>>(
      qkf, qkf + 1024, nullptr, Sc, Dd, Nn, 2048, 2048, 0.03125f, lsum);
  // av = P @ v  (fp32 out): [8192][1024], K=8192
  gemm_mx<0, 0, 0><<<dim3(64, 8), 256, 0, stream>>>(
      Sc, vtf, nullptr, avf, Nn, Dd, Nn, Nn, 1.f, nullptr);

  beta_combine<<<Nn, 256, 0, stream>>>(xrb, avf, lsum, W_beta, b_beta, ub);

  gemm_bt<0><<<dim3(64, 8), 256, 0, stream>>>(
      ub, wft, b_fc, out, Dd, Cc_, Dd, Dd, 1.f);
}